// Round 1
// baseline (500.626 us; speedup 1.0000x reference)
//
#include <hip/hip_runtime.h>
#include <hip/hip_bf16.h>
#include <stdint.h>

#define CATS  32
#define DI    1024
#define DO    1024
#define NB    64
#define ST    512

typedef float  f32x4  __attribute__((ext_vector_type(4)));
typedef short  bf16x8 __attribute__((ext_vector_type(8)));

__device__ __forceinline__ unsigned short f2bf(float f) {
    union { float f; unsigned int u; } v;
    v.f = f;
    // round-to-nearest-even (inputs are finite normals; no NaN handling needed)
    unsigned int r = v.u + 0x7FFFu + ((v.u >> 16) & 1u);
    return (unsigned short)(r >> 16);
}

// ---------------- Pass 1: W (C,I,O) fp32  ->  Wt (C,O,I) bf16 ----------------
// 64x64 tiles per block, 256 threads. LDS stride 65 floats -> conflict-free-ish.
__global__ __launch_bounds__(256) void wt_transpose_kernel(
        const float* __restrict__ W, unsigned short* __restrict__ Wt) {
    __shared__ float tile[64 * 65];
    const int c  = blockIdx.z;
    const int i0 = blockIdx.y * 64;
    const int o0 = blockIdx.x * 64;
    const float* Wc = W + (size_t)c * DI * DO;
    const int tid = threadIdx.x;

    const int f  = tid & 15;   // float4 slot along o
    const int r0 = tid >> 4;   // 0..15 along i
    #pragma unroll
    for (int rr = 0; rr < 4; ++rr) {
        const int r = r0 + rr * 16;
        const f32x4 v = *(const f32x4*)(Wc + (size_t)(i0 + r) * DO + (o0 + 4 * f));
        #pragma unroll
        for (int j = 0; j < 4; ++j)
            tile[r * 65 + 4 * f + j] = v[j];
    }
    __syncthreads();

    const int g   = tid & 7;    // 8-elem group along i
    const int ol0 = tid >> 3;   // 0..31 along o
    unsigned short* WtC = Wt + (size_t)c * DO * DI;
    #pragma unroll
    for (int oo = 0; oo < 2; ++oo) {
        const int ol = ol0 + oo * 32;
        unsigned int w[4];
        #pragma unroll
        for (int j = 0; j < 4; ++j) {
            const unsigned short lo = f2bf(tile[(8 * g + 2 * j + 0) * 65 + ol]);
            const unsigned short hi = f2bf(tile[(8 * g + 2 * j + 1) * 65 + ol]);
            w[j] = (unsigned int)lo | ((unsigned int)hi << 16);
        }
        uint4 pk;
        pk.x = w[0]; pk.y = w[1]; pk.z = w[2]; pk.w = w[3];
        *(uint4*)(WtC + (size_t)(o0 + ol) * DI + (i0 + 8 * g)) = pk;
    }
}

// ---------------- Pass 2: per-category GEMM with bf16 MFMA ----------------
// Block = 256 threads (4 waves), tile 128(M=t) x 128(N=o), BK=32.
// A (x fp32) -> cvt bf16 -> double-buffered LDS [M][K], k-contiguous.
// B (Wt bf16, k-contiguous) -> direct global->register fragments, no LDS.
#define BM 128
#define BN 128
#define BK 32
#define AST 40            // LDS A row stride (32 + 8 pad) -> 80B rows, 2-way reads (free)
#define KSTEPS (DI / BK)  // 32

__global__ __launch_bounds__(256) void cat_gemm_kernel(
        const float* __restrict__ x, const int* __restrict__ cat_ids,
        const unsigned short* __restrict__ Wt, const float* __restrict__ bias,
        float* __restrict__ out) {
    __shared__ __align__(16) unsigned short As[2][BM * AST];  // 20.5 KB

    const int b     = blockIdx.z;
    const int mbase = blockIdx.y * BM;   // t offset
    const int nbase = blockIdx.x * BN;   // o offset
    const int cat   = cat_ids[b];

    const float*          xB = x  + ((size_t)b * ST + mbase) * DI;
    const unsigned short* Wc = Wt + ((size_t)cat * DO + nbase) * DI;

    const int tid  = threadIdx.x;
    const int lane = tid & 63;
    const int wv   = tid >> 6;
    const int wr   = wv >> 1;      // wave row (M)
    const int wc   = wv & 1;       // wave col (N)
    const int l15  = lane & 15;
    const int kg   = lane >> 4;    // MFMA k-quad

    const int sf  = tid & 7;       // staging float4 slot in k
    const int sr0 = tid >> 3;      // staging row base 0..31 (+32*it)

    const unsigned short* bptr[4];
    #pragma unroll
    for (int ni = 0; ni < 4; ++ni)
        bptr[ni] = Wc + (size_t)(wc * 64 + ni * 16 + l15) * DI + kg * 8;

    f32x4 acc[4][4];
    #pragma unroll
    for (int mi = 0; mi < 4; ++mi)
        #pragma unroll
        for (int ni = 0; ni < 4; ++ni)
            acc[mi][ni] = (f32x4){0.f, 0.f, 0.f, 0.f};

    f32x4  xg[4];
    bf16x8 bcur[4], bnxt[4];

    // prologue: k0 = 0
    #pragma unroll
    for (int it = 0; it < 4; ++it)
        xg[it] = *(const f32x4*)(xB + (size_t)(sr0 + 32 * it) * DI + 4 * sf);
    #pragma unroll
    for (int ni = 0; ni < 4; ++ni)
        bcur[ni] = *(const bf16x8*)(bptr[ni]);

    #pragma unroll
    for (int it = 0; it < 4; ++it) {
        ushort4 w;
        w.x = f2bf(xg[it][0]); w.y = f2bf(xg[it][1]);
        w.z = f2bf(xg[it][2]); w.w = f2bf(xg[it][3]);
        *(ushort4*)&As[0][(sr0 + 32 * it) * AST + 4 * sf] = w;
    }
    __syncthreads();

    int buf = 0;
    #pragma unroll 1
    for (int step = 0; step < KSTEPS; ++step) {
        const int  k0n  = (step + 1) * BK;
        const bool more = (step + 1 < KSTEPS);
        if (more) {
            #pragma unroll
            for (int it = 0; it < 4; ++it)
                xg[it] = *(const f32x4*)(xB + (size_t)(sr0 + 32 * it) * DI + k0n + 4 * sf);
            #pragma unroll
            for (int ni = 0; ni < 4; ++ni)
                bnxt[ni] = *(const bf16x8*)(bptr[ni] + k0n);
        }

        bf16x8 af[4];
        #pragma unroll
        for (int mi = 0; mi < 4; ++mi)
            af[mi] = *(const bf16x8*)&As[buf][(wr * 64 + mi * 16 + l15) * AST + kg * 8];

        #pragma unroll
        for (int mi = 0; mi < 4; ++mi)
            #pragma unroll
            for (int ni = 0; ni < 4; ++ni)
                acc[mi][ni] = __builtin_amdgcn_mfma_f32_16x16x32_bf16(
                                  af[mi], bcur[ni], acc[mi][ni], 0, 0, 0);

        if (more) {
            #pragma unroll
            for (int it = 0; it < 4; ++it) {
                ushort4 w;
                w.x = f2bf(xg[it][0]); w.y = f2bf(xg[it][1]);
                w.z = f2bf(xg[it][2]); w.w = f2bf(xg[it][3]);
                *(ushort4*)&As[buf ^ 1][(sr0 + 32 * it) * AST + 4 * sf] = w;
            }
            #pragma unroll
            for (int ni = 0; ni < 4; ++ni)
                bcur[ni] = bnxt[ni];
        }
        __syncthreads();
        buf ^= 1;
    }

    // epilogue: C/D layout col = lane&15, row = (lane>>4)*4 + r
    float bs[4];
    #pragma unroll
    for (int ni = 0; ni < 4; ++ni)
        bs[ni] = bias[cat * DO + nbase + wc * 64 + ni * 16 + l15];

    #pragma unroll
    for (int mi = 0; mi < 4; ++mi) {
        const int rowb = mbase + wr * 64 + mi * 16 + kg * 4;
        #pragma unroll
        for (int r = 0; r < 4; ++r) {
            float* orow = out + ((size_t)b * ST + rowb + r) * DO
                              + nbase + wc * 64 + l15;
            #pragma unroll
            for (int ni = 0; ni < 4; ++ni)
                orow[ni * 16] = acc[mi][ni][r] + bs[ni];
        }
    }
}

// ---------------- Fallback (workspace too small): correct fp32 path ----------------
__global__ __launch_bounds__(256) void naive_kernel(
        const float* __restrict__ x, const int* __restrict__ cat_ids,
        const float* __restrict__ W, const float* __restrict__ bias,
        float* __restrict__ out) {
    const int bt = blockIdx.x;
    const int b  = bt >> 9;     // / 512
    const int t  = bt & 511;
    const int cat = cat_ids[b];
    const float* xr = x + ((size_t)b * ST + t) * DI;
    const float* Wc = W + (size_t)cat * DI * DO;
    const int o = threadIdx.x;
    float a0 = bias[cat * DO + o];
    float a1 = bias[cat * DO + o + 256];
    float a2 = bias[cat * DO + o + 512];
    float a3 = bias[cat * DO + o + 768];
    for (int i = 0; i < DI; ++i) {
        const float xv = xr[i];
        const float* wrow = Wc + (size_t)i * DO;
        a0 += xv * wrow[o];
        a1 += xv * wrow[o + 256];
        a2 += xv * wrow[o + 512];
        a3 += xv * wrow[o + 768];
    }
    float* orow = out + ((size_t)b * ST + t) * DO;
    orow[o] = a0; orow[o + 256] = a1; orow[o + 512] = a2; orow[o + 768] = a3;
}

extern "C" void kernel_launch(void* const* d_in, const int* in_sizes, int n_in,
                              void* d_out, int out_size, void* d_ws, size_t ws_size,
                              hipStream_t stream) {
    const float* x    = (const float*)d_in[0];
    const int*   cats = (const int*)d_in[1];
    const float* W    = (const float*)d_in[2];
    const float* bias = (const float*)d_in[3];
    float*       out  = (float*)d_out;

    const size_t wt_bytes = (size_t)CATS * DI * DO * sizeof(unsigned short); // 67 MB
    if (ws_size >= wt_bytes) {
        unsigned short* Wt = (unsigned short*)d_ws;
        wt_transpose_kernel<<<dim3(DO / 64, DI / 64, CATS), 256, 0, stream>>>(W, Wt);
        cat_gemm_kernel<<<dim3(DO / BN, ST / BM, NB), 256, 0, stream>>>(x, cats, Wt, bias, out);
    } else {
        naive_kernel<<<NB * ST, 256, 0, stream>>>(x, cats, W, bias, out);
    }
}